// Round 1
// baseline (209.347 us; speedup 1.0000x reference)
//
#include <hip/hip_runtime.h>
#include <hip/hip_bf16.h>

// DepthLossWithMask: loss = sum(|output - label0| * label1) / count(label0 != 0)
// B,C,H,W = 16,15,256,256 -> N = 15,728,640 elements (divisible by 4).
// Memory-bound: 3 * N * 4B = 188.7 MB read. Roofline @6.3 TB/s ~= 30 us.

#define REDUCE_BLOCKS 2048
#define REDUCE_THREADS 256

struct Accum {
    double loss;          // offset 0
    unsigned int count;   // offset 8
};

__global__ __launch_bounds__(REDUCE_THREADS)
void depth_loss_reduce(const float4* __restrict__ out,
                       const float4* __restrict__ l0,
                       const float4* __restrict__ l1,
                       Accum* __restrict__ acc,
                       int n4) {
    float sum = 0.0f;
    unsigned int cnt = 0;

    int stride = gridDim.x * blockDim.x;
    for (int i = blockIdx.x * blockDim.x + threadIdx.x; i < n4; i += stride) {
        float4 o = out[i];
        float4 a = l0[i];
        float4 w = l1[i];
        sum += fabsf(o.x - a.x) * w.x;
        sum += fabsf(o.y - a.y) * w.y;
        sum += fabsf(o.z - a.z) * w.z;
        sum += fabsf(o.w - a.w) * w.w;
        cnt += (a.x != 0.0f) + (a.y != 0.0f) + (a.z != 0.0f) + (a.w != 0.0f);
    }

    // wave-64 butterfly reduce
    #pragma unroll
    for (int off = 32; off > 0; off >>= 1) {
        sum += __shfl_down(sum, off, 64);
        cnt += __shfl_down(cnt, off, 64);
    }

    __shared__ float  sv[REDUCE_THREADS / 64];
    __shared__ unsigned int sc[REDUCE_THREADS / 64];
    int lane = threadIdx.x & 63;
    int wid  = threadIdx.x >> 6;
    if (lane == 0) { sv[wid] = sum; sc[wid] = cnt; }
    __syncthreads();

    if (threadIdx.x == 0) {
        float bs = 0.0f;
        unsigned int bc = 0;
        #pragma unroll
        for (int i = 0; i < REDUCE_THREADS / 64; ++i) { bs += sv[i]; bc += sc[i]; }
        atomicAdd(&acc->loss, (double)bs);
        atomicAdd(&acc->count, bc);
    }
}

__global__ void depth_loss_finalize(const Accum* __restrict__ acc,
                                    float* __restrict__ out) {
    unsigned int c = acc->count;
    double l = acc->loss;
    out[0] = (c == 0) ? 0.0f : (float)(l / (double)c);
}

extern "C" void kernel_launch(void* const* d_in, const int* in_sizes, int n_in,
                              void* d_out, int out_size, void* d_ws, size_t ws_size,
                              hipStream_t stream) {
    const float* output = (const float*)d_in[0];
    const float* label0 = (const float*)d_in[1];
    const float* label1 = (const float*)d_in[2];
    int n = in_sizes[0];           // 15,728,640
    int n4 = n >> 2;               // divisible by 4

    Accum* acc = (Accum*)d_ws;
    hipMemsetAsync(d_ws, 0, sizeof(Accum), stream);

    depth_loss_reduce<<<REDUCE_BLOCKS, REDUCE_THREADS, 0, stream>>>(
        (const float4*)output, (const float4*)label0, (const float4*)label1,
        acc, n4);

    depth_loss_finalize<<<1, 1, 0, stream>>>(acc, (float*)d_out);
}

// Round 2
// 192.482 us; speedup vs baseline: 1.0876x; 1.0876x over previous
//
#include <hip/hip_runtime.h>
#include <hip/hip_bf16.h>

// DepthLossWithMask: loss = sum(|output - label0| * label1) / count(label0 != 0)
// N = 16*15*256*256 = 15,728,640 floats -> n4 = 3,932,160 float4.
// Memory-bound: 188.7 MB read. R1 showed latency-bound (VGPR=12, 3 loads in
// flight). Fix: 8 float4 per thread per array = 24 outstanding dwordx4 loads.

#define REDUCE_THREADS 256
#define EPT 8   // float4 chunks per thread; block covers 256*8 = 2048 float4

struct Accum {
    double loss;          // offset 0
    unsigned int count;   // offset 8
};

__global__ __launch_bounds__(REDUCE_THREADS)
void depth_loss_reduce(const float4* __restrict__ out,
                       const float4* __restrict__ l0,
                       const float4* __restrict__ l1,
                       Accum* __restrict__ acc,
                       int n4) {
    const int base = blockIdx.x * (REDUCE_THREADS * EPT) + threadIdx.x;

    float4 o[EPT], a[EPT], w[EPT];
    // Issue all loads up front -> 24 independent global_load_dwordx4 in flight.
    #pragma unroll
    for (int k = 0; k < EPT; ++k) {
        int i = base + k * REDUCE_THREADS;
        bool ok = (i < n4);
        int j = ok ? i : 0;
        o[k] = out[j];
        a[k] = l0[j];
        w[k] = l1[j];
        if (!ok) {  // neutralize out-of-range chunk (doesn't occur at N=15.7M)
            a[k] = make_float4(0.f, 0.f, 0.f, 0.f);
            o[k] = make_float4(0.f, 0.f, 0.f, 0.f);
            w[k] = make_float4(0.f, 0.f, 0.f, 0.f);
        }
    }

    float sum = 0.0f;
    unsigned int cnt = 0;
    #pragma unroll
    for (int k = 0; k < EPT; ++k) {
        sum += fabsf(o[k].x - a[k].x) * w[k].x;
        sum += fabsf(o[k].y - a[k].y) * w[k].y;
        sum += fabsf(o[k].z - a[k].z) * w[k].z;
        sum += fabsf(o[k].w - a[k].w) * w[k].w;
        cnt += (a[k].x != 0.0f) + (a[k].y != 0.0f) +
               (a[k].z != 0.0f) + (a[k].w != 0.0f);
    }

    // wave-64 butterfly reduce
    #pragma unroll
    for (int off = 32; off > 0; off >>= 1) {
        sum += __shfl_down(sum, off, 64);
        cnt += __shfl_down(cnt, off, 64);
    }

    __shared__ float        sv[REDUCE_THREADS / 64];
    __shared__ unsigned int sc[REDUCE_THREADS / 64];
    int lane = threadIdx.x & 63;
    int wid  = threadIdx.x >> 6;
    if (lane == 0) { sv[wid] = sum; sc[wid] = cnt; }
    __syncthreads();

    if (threadIdx.x == 0) {
        float bs = 0.0f;
        unsigned int bc = 0;
        #pragma unroll
        for (int i = 0; i < REDUCE_THREADS / 64; ++i) { bs += sv[i]; bc += sc[i]; }
        atomicAdd(&acc->loss, (double)bs);
        atomicAdd(&acc->count, bc);
    }
}

__global__ void depth_loss_finalize(const Accum* __restrict__ acc,
                                    float* __restrict__ out) {
    unsigned int c = acc->count;
    double l = acc->loss;
    out[0] = (c == 0) ? 0.0f : (float)(l / (double)c);
}

extern "C" void kernel_launch(void* const* d_in, const int* in_sizes, int n_in,
                              void* d_out, int out_size, void* d_ws, size_t ws_size,
                              hipStream_t stream) {
    const float* output = (const float*)d_in[0];
    const float* label0 = (const float*)d_in[1];
    const float* label1 = (const float*)d_in[2];
    int n = in_sizes[0];           // 15,728,640
    int n4 = n >> 2;               // 3,932,160 float4

    Accum* acc = (Accum*)d_ws;
    hipMemsetAsync(d_ws, 0, sizeof(Accum), stream);

    int per_block = REDUCE_THREADS * EPT;           // 2048 float4 per block
    int blocks = (n4 + per_block - 1) / per_block;  // 1920

    depth_loss_reduce<<<blocks, REDUCE_THREADS, 0, stream>>>(
        (const float4*)output, (const float4*)label0, (const float4*)label1,
        acc, n4);

    depth_loss_finalize<<<1, 1, 0, stream>>>(acc, (float*)d_out);
}

// Round 3
// 187.214 us; speedup vs baseline: 1.1182x; 1.0281x over previous
//
#include <hip/hip_runtime.h>
#include <hip/hip_bf16.h>

// DepthLossWithMask: loss = sum(|output - label0| * label1) / count(label0 != 0)
// N = 16*15*256*256 = 15,728,640 floats -> n4 = 3,932,160 float4.
//
// R2 finding: runtime (75us) invariant even when data is fully L2/L3-resident
// (hbm_bytes 123KB replays) => bottleneck was ~1920 same-cache-line global
// atomics (~40ns each serialized). R3: atomic-free two-stage reduction.

#define REDUCE_THREADS 256
#define EPT 8   // float4 chunks per thread; block covers 256*8 = 2048 float4

struct Partial {
    float s;
    unsigned int c;
};

__global__ __launch_bounds__(REDUCE_THREADS)
void depth_loss_stage1(const float4* __restrict__ out,
                       const float4* __restrict__ l0,
                       const float4* __restrict__ l1,
                       Partial* __restrict__ partials,
                       int n4) {
    const int base = blockIdx.x * (REDUCE_THREADS * EPT) + threadIdx.x;

    float4 o[EPT], a[EPT], w[EPT];
    #pragma unroll
    for (int k = 0; k < EPT; ++k) {
        int i = base + k * REDUCE_THREADS;
        bool ok = (i < n4);
        int j = ok ? i : 0;
        o[k] = out[j];
        a[k] = l0[j];
        w[k] = l1[j];
        if (!ok) {
            a[k] = make_float4(0.f, 0.f, 0.f, 0.f);
            o[k] = make_float4(0.f, 0.f, 0.f, 0.f);
            w[k] = make_float4(0.f, 0.f, 0.f, 0.f);
        }
    }

    float sum = 0.0f;
    unsigned int cnt = 0;
    #pragma unroll
    for (int k = 0; k < EPT; ++k) {
        sum += fabsf(o[k].x - a[k].x) * w[k].x;
        sum += fabsf(o[k].y - a[k].y) * w[k].y;
        sum += fabsf(o[k].z - a[k].z) * w[k].z;
        sum += fabsf(o[k].w - a[k].w) * w[k].w;
        cnt += (a[k].x != 0.0f) + (a[k].y != 0.0f) +
               (a[k].z != 0.0f) + (a[k].w != 0.0f);
    }

    // wave-64 butterfly reduce
    #pragma unroll
    for (int off = 32; off > 0; off >>= 1) {
        sum += __shfl_down(sum, off, 64);
        cnt += __shfl_down(cnt, off, 64);
    }

    __shared__ float        sv[REDUCE_THREADS / 64];
    __shared__ unsigned int sc[REDUCE_THREADS / 64];
    int lane = threadIdx.x & 63;
    int wid  = threadIdx.x >> 6;
    if (lane == 0) { sv[wid] = sum; sc[wid] = cnt; }
    __syncthreads();

    if (threadIdx.x == 0) {
        float bs = 0.0f;
        unsigned int bc = 0;
        #pragma unroll
        for (int i = 0; i < REDUCE_THREADS / 64; ++i) { bs += sv[i]; bc += sc[i]; }
        Partial p; p.s = bs; p.c = bc;
        partials[blockIdx.x] = p;   // plain 8B store, no contention
    }
}

__global__ __launch_bounds__(REDUCE_THREADS)
void depth_loss_stage2(const Partial* __restrict__ partials,
                       int nblocks,
                       float* __restrict__ out) {
    double sum = 0.0;
    unsigned int cnt = 0;
    for (int i = threadIdx.x; i < nblocks; i += REDUCE_THREADS) {
        Partial p = partials[i];
        sum += (double)p.s;
        cnt += p.c;
    }

    #pragma unroll
    for (int off = 32; off > 0; off >>= 1) {
        sum += __shfl_down(sum, off, 64);
        cnt += __shfl_down(cnt, off, 64);
    }

    __shared__ double       sv[REDUCE_THREADS / 64];
    __shared__ unsigned int sc[REDUCE_THREADS / 64];
    int lane = threadIdx.x & 63;
    int wid  = threadIdx.x >> 6;
    if (lane == 0) { sv[wid] = sum; sc[wid] = cnt; }
    __syncthreads();

    if (threadIdx.x == 0) {
        double bs = 0.0;
        unsigned int bc = 0;
        #pragma unroll
        for (int i = 0; i < REDUCE_THREADS / 64; ++i) { bs += sv[i]; bc += sc[i]; }
        out[0] = (bc == 0) ? 0.0f : (float)(bs / (double)bc);
    }
}

extern "C" void kernel_launch(void* const* d_in, const int* in_sizes, int n_in,
                              void* d_out, int out_size, void* d_ws, size_t ws_size,
                              hipStream_t stream) {
    const float* output = (const float*)d_in[0];
    const float* label0 = (const float*)d_in[1];
    const float* label1 = (const float*)d_in[2];
    int n = in_sizes[0];           // 15,728,640
    int n4 = n >> 2;               // 3,932,160 float4

    int per_block = REDUCE_THREADS * EPT;           // 2048 float4 per block
    int blocks = (n4 + per_block - 1) / per_block;  // 1920

    Partial* partials = (Partial*)d_ws;             // 1920*8 = 15 KB, all written

    depth_loss_stage1<<<blocks, REDUCE_THREADS, 0, stream>>>(
        (const float4*)output, (const float4*)label0, (const float4*)label1,
        partials, n4);

    depth_loss_stage2<<<1, REDUCE_THREADS, 0, stream>>>(
        partials, blocks, (float*)d_out);
}